// Round 1
// baseline (283.836 us; speedup 1.0000x reference)
//
#include <hip/hip_runtime.h>
#include <hip/hip_fp16.h>

#define N_NODES  100000
#define N_EDGES  1600000
#define N_GRAPHS 2048
#define VOCAB    1000
#define EMBED    64
#define HID      64
#define N_CL     2
#define CAP      64     // max degree capacity (deg~Poisson(16); P(>=64)~3e-22/node)
#define NBLK     391    // ceil(N_NODES/256)
#define EBLK2    3125   // N_EDGES/512: 2 edges per thread
#define VBLK     63     // ceil(VOCAB*16/256): E-gemm blocks
#define NSWEEP   8
#define RANGE    12500  // N_NODES / NSWEEP

typedef __half2 h2;

// pack float4 -> 4 fp16 (8B)
__device__ inline uint2 pack_h4(float4 a) {
    h2 lo = __float22half2_rn(make_float2(a.x, a.y));
    h2 hi = __float22half2_rn(make_float2(a.z, a.w));
    uint2 r;
    r.x = *reinterpret_cast<unsigned*>(&lo);
    r.y = *reinterpret_cast<unsigned*>(&hi);
    return r;
}

// packed fp16 accumulate: 4x v_pk_add_f16 per 16B row
__device__ inline void acc_h8(h2 acc[4], uint4 raw) {
    acc[0] = __hadd2(acc[0], *reinterpret_cast<h2*>(&raw.x));
    acc[1] = __hadd2(acc[1], *reinterpret_cast<h2*>(&raw.y));
    acc[2] = __hadd2(acc[2], *reinterpret_cast<h2*>(&raw.z));
    acc[3] = __hadd2(acc[3], *reinterpret_cast<h2*>(&raw.w));
}

// convert 4x half2 -> 2x float4
__device__ inline void h8_to_f(const h2 acc[4], float4& A, float4& B) {
    float2 f0 = __half22float2(acc[0]);
    float2 f1 = __half22float2(acc[1]);
    float2 f2 = __half22float2(acc[2]);
    float2 f3 = __half22float2(acc[3]);
    A.x = f0.x; A.y = f0.y; A.z = f1.x; A.w = f1.y;
    B.x = f2.x; B.y = f2.y; B.z = f3.x; B.w = f3.y;
}

__device__ inline void xor_reduce8(float4& A, float4& B) {
#pragma unroll
    for (int m = 8; m <= 32; m <<= 1) {
        A.x += __shfl_xor(A.x, m, 64); A.y += __shfl_xor(A.y, m, 64);
        A.z += __shfl_xor(A.z, m, 64); A.w += __shfl_xor(A.w, m, 64);
        B.x += __shfl_xor(B.x, m, 64); B.y += __shfl_xor(B.y, m, 64);
        B.z += __shfl_xor(B.z, m, 64); B.w += __shfl_xor(B.w, m, 64);
    }
}

// ================= bucket fill: XCD-aligned target-range sweeps + gb + E=emb@W1 ==================
// r15-proven sweep structure; this round: NON-TEMPORAL edge-stream loads (stop the 6.4MB/sweep col
// stream from thrashing the XCD-local 3.2MB slots region in 4MB L2 -> kills the 5x write
// amplification seen in rocprof: WRITE_SIZE 79MB for ~15MB of dirty slot lines) + 2 edges/thread.
__global__ __launch_bounds__(256) void k_fill_slots(const int* __restrict__ row, const int* __restrict__ col,
                                                    int* __restrict__ cnt, int* __restrict__ slots,
                                                    const int* __restrict__ batch, int* __restrict__ start,
                                                    const float* __restrict__ emb, const float* __restrict__ W1,
                                                    float* __restrict__ E) {
    int bid = blockIdx.x;
    if (bid < NSWEEP * EBLK2) {     // ---- fill sweep (XCD-interleaved, 2 edges/thread, nt loads) ----
        int sweep = bid & (NSWEEP - 1);
        int t = (bid >> 3) * 256 + threadIdx.x;          // pair index
        const long long* col2 = (const long long*)col;
        long long cc = __builtin_nontemporal_load(col2 + t);   // col[2t], col[2t+1] — evict-first
        int ca = (int)(cc & 0xffffffffLL);
        int cb = (int)((unsigned long long)cc >> 32);
        unsigned lo = (unsigned)(sweep * RANGE);
        if ((unsigned)(ca - lo) < (unsigned)RANGE) {
            int r = __builtin_nontemporal_load(row + 2 * t);
            int pos = atomicAdd(&cnt[ca], 1);
            if (pos < CAP) slots[ca * CAP + pos] = r;
        }
        if ((unsigned)(cb - lo) < (unsigned)RANGE) {
            int r = __builtin_nontemporal_load(row + 2 * t + 1);
            int pos = atomicAdd(&cnt[cb], 1);
            if (pos < CAP) slots[cb * CAP + pos] = r;
        }
    } else if (bid < NSWEEP * EBLK2 + NBLK) {  // ---- graph boundaries from sorted batch ----
        int v = (bid - NSWEEP * EBLK2) * 256 + threadIdx.x;
        if (v >= N_NODES) return;
        int b = batch[v];
        int pb = (v == 0) ? -1 : batch[v - 1];
        for (int g = pb + 1; g <= b; ++g) start[g] = v;
        if (v == N_NODES - 1)
            for (int g = b + 1; g <= N_GRAPHS; ++g) start[g] = N_NODES;
    } else {                        // ---- E[j] = emb[j] @ W1 (1000x64, float4/thread) ----
        int t = (bid - NSWEEP * EBLK2 - NBLK) * 256 + threadIdx.x;
        int j = t >> 4;
        int f4 = t & 15;
        if (j >= VOCAB) return;
        const float4* W4 = (const float4*)W1;
        const float* er = emb + j * EMBED;
        float4 acc = make_float4(0.f, 0.f, 0.f, 0.f);
#pragma unroll 8
        for (int k = 0; k < EMBED; ++k) {
            float hv = er[k];
            float4 w = W4[k * 16 + f4];
            acc.x += hv * w.x; acc.y += hv * w.y; acc.z += hv * w.z; acc.w += hv * w.w;
        }
        ((float4*)E)[t] = acc;
    }
}

// ================= tn1[v] = fp16( rsqrt(cnt[v]+1) * E[x[v]] ) =================
__global__ __launch_bounds__(256) void k_tn1(const int* __restrict__ x, const int* __restrict__ cnt,
                                             const float* __restrict__ E, uint2* __restrict__ tn) {
    int t = blockIdx.x * 256 + threadIdx.x;      // exact: N_NODES*16
    int v = t >> 4;
    int f4 = t & 15;
    float d = rsqrtf((float)(cnt[v] + 1));
    float4 a = ((const float4*)E)[x[v] * 16 + f4];
    a.x *= d; a.y *= d; a.z *= d; a.w *= d;
    tn[t] = pack_h4(a);
}

// ================= fused: layer-1 aggregate (fp16 pk-add) + finalize + layer-2 GEMM ==============
// 2 nodes/wave; lane = (es[0..7], fg[0..7]); packed-fp16 per-lane partials (<=8 summands), fp32 reduce
__global__ __launch_bounds__(256) void k_agg_gemm(const uint4* __restrict__ tn,
                                                  const int* __restrict__ cnt,
                                                  const int* __restrict__ slots,
                                                  const float* __restrict__ bias,
                                                  const float* __restrict__ W2,
                                                  __half* __restrict__ tn2) {
    __shared__ float hrow[8][HID];
    int wid = threadIdx.x >> 6;
    int lane = threadIdx.x & 63;
    int fg = lane & 7;
    int es = lane >> 3;
    int v0 = blockIdx.x * 8 + wid * 2;
    int v1 = v0 + 1;
    int c0 = cnt[v0], c1 = cnt[v1];
    int n0 = min(c0, CAP), n1 = min(c1, CAP);
    const int* sl0 = slots + v0 * CAP;
    const int* sl1 = slots + v1 * CAP;
    h2 z = __float2half2_rn(0.f);
    h2 a0[4] = {z, z, z, z};
    h2 a1[4] = {z, z, z, z};
    if (es == 0) acc_h8(a0, tn[v0 * 8 + fg]);   // self loop v0
    if (es == 1) acc_h8(a1, tn[v1 * 8 + fg]);   // self loop v1
    int m = max(n0, n1);
    int i = 0;
    for (; i + 16 <= m; i += 16) {
        int ia = i + es, ib = i + 8 + es;
        if (ia < n0) { uint4 r = tn[sl0[ia] * 8 + fg]; acc_h8(a0, r); }
        if (ia < n1) { uint4 r = tn[sl1[ia] * 8 + fg]; acc_h8(a1, r); }
        if (ib < n0) { uint4 r = tn[sl0[ib] * 8 + fg]; acc_h8(a0, r); }
        if (ib < n1) { uint4 r = tn[sl1[ib] * 8 + fg]; acc_h8(a1, r); }
    }
    for (; i < m; i += 8) {
        int ia = i + es;
        if (ia < n0) { uint4 r = tn[sl0[ia] * 8 + fg]; acc_h8(a0, r); }
        if (ia < n1) { uint4 r = tn[sl1[ia] * 8 + fg]; acc_h8(a1, r); }
    }
    float4 a0A, a0B, a1A, a1B;
    h8_to_f(a0, a0A, a0B);
    h8_to_f(a1, a1A, a1B);
    xor_reduce8(a0A, a0B);
    xor_reduce8(a1A, a1B);
    float d0 = rsqrtf((float)(c0 + 1));
    float d1 = rsqrtf((float)(c1 + 1));
    float4 bA = ((const float4*)bias)[fg * 2 + 0];
    float4 bB = ((const float4*)bias)[fg * 2 + 1];
    if (es == 0) {
        float4 oA, oB;
        oA.x = fmaxf(d0 * a0A.x + bA.x, 0.f); oA.y = fmaxf(d0 * a0A.y + bA.y, 0.f);
        oA.z = fmaxf(d0 * a0A.z + bA.z, 0.f); oA.w = fmaxf(d0 * a0A.w + bA.w, 0.f);
        oB.x = fmaxf(d0 * a0B.x + bB.x, 0.f); oB.y = fmaxf(d0 * a0B.y + bB.y, 0.f);
        oB.z = fmaxf(d0 * a0B.z + bB.z, 0.f); oB.w = fmaxf(d0 * a0B.w + bB.w, 0.f);
        ((float4*)&hrow[wid * 2][fg * 8])[0] = oA;
        ((float4*)&hrow[wid * 2][fg * 8])[1] = oB;
    }
    if (es == 1) {
        float4 oA, oB;
        oA.x = fmaxf(d1 * a1A.x + bA.x, 0.f); oA.y = fmaxf(d1 * a1A.y + bA.y, 0.f);
        oA.z = fmaxf(d1 * a1A.z + bA.z, 0.f); oA.w = fmaxf(d1 * a1A.w + bA.w, 0.f);
        oB.x = fmaxf(d1 * a1B.x + bB.x, 0.f); oB.y = fmaxf(d1 * a1B.y + bB.y, 0.f);
        oB.z = fmaxf(d1 * a1B.z + bB.z, 0.f); oB.w = fmaxf(d1 * a1B.w + bB.w, 0.f);
        ((float4*)&hrow[wid * 2 + 1][fg * 8])[0] = oA;
        ((float4*)&hrow[wid * 2 + 1][fg * 8])[1] = oB;
    }
    __syncthreads();
    // ---- layer-2 GEMM: lane computes feature `lane` for both nodes ----
    // float4 LDS reads: 32x ds_read_b128 per thread instead of 128x ds_read_b32
    const float4* h04 = (const float4*)hrow[wid * 2];
    const float4* h14 = (const float4*)hrow[wid * 2 + 1];
    float s0 = 0.f, s1 = 0.f;
#pragma unroll 4
    for (int k4 = 0; k4 < 16; ++k4) {
        float4 ha = h04[k4];
        float4 hb = h14[k4];
        int k = k4 * 4;
        float w0 = W2[(k + 0) * HID + lane];
        float w1 = W2[(k + 1) * HID + lane];
        float w2 = W2[(k + 2) * HID + lane];
        float w3 = W2[(k + 3) * HID + lane];
        s0 += ha.x * w0 + ha.y * w1 + ha.z * w2 + ha.w * w3;
        s1 += hb.x * w0 + hb.y * w1 + hb.z * w2 + hb.w * w3;
    }
    tn2[v0 * HID + lane] = __float2half(d0 * s0);
    tn2[v1 * HID + lane] = __float2half(d1 * s1);
}

// ---------------- layer-2 aggregate (fp16 pk-add) — 2 nodes per wave -> h2 (fp32) ----------------
__global__ __launch_bounds__(256) void k_agg(const uint4* __restrict__ tn,
                                             const int* __restrict__ cnt,
                                             const int* __restrict__ slots,
                                             const float* __restrict__ bias,
                                             float* __restrict__ h) {
    int wid = threadIdx.x >> 6;
    int lane = threadIdx.x & 63;
    int fg = lane & 7;
    int es = lane >> 3;
    int v0 = blockIdx.x * 8 + wid * 2;
    int v1 = v0 + 1;
    int c0 = cnt[v0], c1 = cnt[v1];
    int n0 = min(c0, CAP), n1 = min(c1, CAP);
    const int* sl0 = slots + v0 * CAP;
    const int* sl1 = slots + v1 * CAP;
    h2 z = __float2half2_rn(0.f);
    h2 a0[4] = {z, z, z, z};
    h2 a1[4] = {z, z, z, z};
    if (es == 0) acc_h8(a0, tn[v0 * 8 + fg]);
    if (es == 1) acc_h8(a1, tn[v1 * 8 + fg]);
    int m = max(n0, n1);
    int i = 0;
    for (; i + 16 <= m; i += 16) {
        int ia = i + es, ib = i + 8 + es;
        if (ia < n0) { uint4 r = tn[sl0[ia] * 8 + fg]; acc_h8(a0, r); }
        if (ia < n1) { uint4 r = tn[sl1[ia] * 8 + fg]; acc_h8(a1, r); }
        if (ib < n0) { uint4 r = tn[sl0[ib] * 8 + fg]; acc_h8(a0, r); }
        if (ib < n1) { uint4 r = tn[sl1[ib] * 8 + fg]; acc_h8(a1, r); }
    }
    for (; i < m; i += 8) {
        int ia = i + es;
        if (ia < n0) { uint4 r = tn[sl0[ia] * 8 + fg]; acc_h8(a0, r); }
        if (ia < n1) { uint4 r = tn[sl1[ia] * 8 + fg]; acc_h8(a1, r); }
    }
    float4 a0A, a0B, a1A, a1B;
    h8_to_f(a0, a0A, a0B);
    h8_to_f(a1, a1A, a1B);
    xor_reduce8(a0A, a0B);
    xor_reduce8(a1A, a1B);
    float4 bA = ((const float4*)bias)[fg * 2 + 0];
    float4 bB = ((const float4*)bias)[fg * 2 + 1];
    if (es == 0) {
        float d0 = rsqrtf((float)(c0 + 1));
        float4 oA, oB;
        oA.x = fmaxf(d0 * a0A.x + bA.x, 0.f); oA.y = fmaxf(d0 * a0A.y + bA.y, 0.f);
        oA.z = fmaxf(d0 * a0A.z + bA.z, 0.f); oA.w = fmaxf(d0 * a0A.w + bA.w, 0.f);
        oB.x = fmaxf(d0 * a0B.x + bB.x, 0.f); oB.y = fmaxf(d0 * a0B.y + bB.y, 0.f);
        oB.z = fmaxf(d0 * a0B.z + bB.z, 0.f); oB.w = fmaxf(d0 * a0B.w + bB.w, 0.f);
        ((float4*)&h[v0 * HID + fg * 8])[0] = oA;
        ((float4*)&h[v0 * HID + fg * 8])[1] = oB;
    }
    if (es == 1) {
        float d1 = rsqrtf((float)(c1 + 1));
        float4 oA, oB;
        oA.x = fmaxf(d1 * a1A.x + bA.x, 0.f); oA.y = fmaxf(d1 * a1A.y + bA.y, 0.f);
        oA.z = fmaxf(d1 * a1A.z + bA.z, 0.f); oA.w = fmaxf(d1 * a1A.w + bA.w, 0.f);
        oB.x = fmaxf(d1 * a1B.x + bB.x, 0.f); oB.y = fmaxf(d1 * a1B.y + bB.y, 0.f);
        oB.z = fmaxf(d1 * a1B.z + bB.z, 0.f); oB.w = fmaxf(d1 * a1B.w + bB.w, 0.f);
        ((float4*)&h[v1 * HID + fg * 8])[0] = oA;
        ((float4*)&h[v1 * HID + fg * 8])[1] = oB;
    }
}

// ---------------- fused mean-pool + projection ----------------
__global__ __launch_bounds__(256) void k_pool_out(const float* __restrict__ h,
                                                  const int* __restrict__ start,
                                                  const float* __restrict__ Wl,
                                                  const float* __restrict__ bl,
                                                  float* __restrict__ out) {
    int g = (blockIdx.x * 256 + threadIdx.x) >> 6;
    int f = threadIdx.x & 63;
    if (g >= N_GRAPHS) return;
    int s = start[g], e = start[g + 1];
    float acc = 0.f;
    int v = s;
    for (; v + 4 <= e; v += 4) {
        float a0 = h[(v + 0) * HID + f];
        float a1 = h[(v + 1) * HID + f];
        float a2 = h[(v + 2) * HID + f];
        float a3 = h[(v + 3) * HID + f];
        acc += (a0 + a1) + (a2 + a3);
    }
    for (; v < e; ++v) acc += h[v * HID + f];
    float m = acc / fmaxf((float)(e - s), 1.f);
    float p0 = m * Wl[f * N_CL + 0];
    float p1 = m * Wl[f * N_CL + 1];
#pragma unroll
    for (int off = 32; off > 0; off >>= 1) {
        p0 += __shfl_down(p0, off, 64);
        p1 += __shfl_down(p1, off, 64);
    }
    if (f == 0) {
        out[g * N_CL + 0] = p0 + bl[0];
        out[g * N_CL + 1] = p1 + bl[1];
    }
}

extern "C" void kernel_launch(void* const* d_in, const int* in_sizes, int n_in,
                              void* d_out, int out_size, void* d_ws, size_t ws_size,
                              hipStream_t stream) {
    const int*   x     = (const int*)d_in[0];
    const int*   ei    = (const int*)d_in[1];        // [2, E] flat: sources then targets
    const int*   batch = (const int*)d_in[2];
    const float* emb   = (const float*)d_in[3];
    const float* W1    = (const float*)d_in[4];
    const float* b1    = (const float*)d_in[5];
    const float* W2    = (const float*)d_in[6];
    const float* b2    = (const float*)d_in[7];
    const float* Wl    = (const float*)d_in[8];
    const float* bl    = (const float*)d_in[9];
    float* out = (float*)d_out;

    const int* row = ei;             // sources
    const int* col = ei + N_EDGES;   // targets

    // ---- workspace layout (~65 MB) ----
    char* ws = (char*)d_ws;
    size_t off = 0;
    auto alloc = [&](size_t bytes) { char* p = ws + off; off = (off + bytes + 511) & ~(size_t)511; return p; };
    const size_t FEAT_BYTES  = (size_t)N_NODES * HID * sizeof(float);      // 25.6 MB
    const size_t FEATH_BYTES = (size_t)N_NODES * HID * sizeof(__half);     // 12.8 MB
    float* A      = (float*)alloc(FEAT_BYTES);             // tn1 (fp16, low half), later h2 (fp32)
    __half* Bt    = (__half*)alloc(FEATH_BYTES);           // tn2 fp16
    int*   slots  = (int*)  alloc((size_t)N_NODES * CAP * sizeof(int));    // 25.6 MB
    float* E      = (float*)alloc((size_t)VOCAB * HID * sizeof(float));    // 256 KB
    int*   start  = (int*)  alloc((size_t)(N_GRAPHS + 1) * sizeof(int));
    int*   cnt    = (int*)  alloc((size_t)N_NODES * sizeof(int));          // zeroed

    dim3 blk(256);
    dim3 g_fill(NSWEEP * EBLK2 + NBLK + VBLK);    // fill sweeps (2 edges/thread) | gb | E-gemm
    dim3 g_tn1(N_NODES * 16 / 256);               // 6250 exact
    dim3 g_agg(N_NODES / 8);                      // 12500 exact (8 nodes/block, 2/wave)
    dim3 g_po((N_GRAPHS * 64 + 255) / 256);       // 512

    hipMemsetAsync(cnt, 0, (size_t)N_NODES * sizeof(int), stream);

    // ---- single scattered pass, XCD-aligned range sweeps ----
    k_fill_slots<<<g_fill, blk, 0, stream>>>(row, col, cnt, slots, batch, start, emb, W1, E);

    // ---- tn1 = fp16(dinv * E[x]) ----
    k_tn1<<<g_tn1, blk, 0, stream>>>(x, cnt, E, (uint2*)A);

    // ---- layer-1 aggregate (fp16 pk-add, 2 nodes/wave) + layer-2 GEMM (tn2 -> fp16) ----
    k_agg_gemm<<<g_agg, blk, 0, stream>>>((const uint4*)A, cnt, slots, b1, W2, Bt);

    // ---- layer-2 aggregate (fp16 pk-add, 2 nodes/wave) -> h2 fp32 (A reused) ----
    k_agg<<<g_agg, blk, 0, stream>>>((const uint4*)Bt, cnt, slots, b2, A);

    // ---- fused pool + classify ----
    k_pool_out<<<g_po, blk, 0, stream>>>(A, start, Wl, bl, out);
}

// Round 3
// 275.913 us; speedup vs baseline: 1.0287x; 1.0287x over previous
//
#include <hip/hip_runtime.h>
#include <hip/hip_fp16.h>

#define N_NODES  100000
#define N_EDGES  1600000
#define N_GRAPHS 2048
#define VOCAB    1000
#define EMBED    64
#define HID      64
#define N_CL     2
#define CAP      64     // max degree capacity (deg~Poisson(16); P(>=64)~3e-22/node)
#define NBLK     391    // ceil(N_NODES/256)
#define EBLK4    1563   // ceil(N_EDGES/4/256): 4 edges per thread
#define NQUAD    400000 // N_EDGES/4
#define VBLK     63     // ceil(VOCAB*16/256): E-gemm blocks
#define NSWEEP   8
#define RANGE    12500  // N_NODES / NSWEEP

typedef __half2 h2;
typedef int i4 __attribute__((ext_vector_type(4)));   // clang ext_vector: valid for nontemporal builtins

// pack float4 -> 4 fp16 (8B)
__device__ inline uint2 pack_h4(float4 a) {
    h2 lo = __float22half2_rn(make_float2(a.x, a.y));
    h2 hi = __float22half2_rn(make_float2(a.z, a.w));
    uint2 r;
    r.x = *reinterpret_cast<unsigned*>(&lo);
    r.y = *reinterpret_cast<unsigned*>(&hi);
    return r;
}

// packed fp16 accumulate: 4x v_pk_add_f16 per 16B row
__device__ inline void acc_h8(h2 acc[4], uint4 raw) {
    acc[0] = __hadd2(acc[0], *reinterpret_cast<h2*>(&raw.x));
    acc[1] = __hadd2(acc[1], *reinterpret_cast<h2*>(&raw.y));
    acc[2] = __hadd2(acc[2], *reinterpret_cast<h2*>(&raw.z));
    acc[3] = __hadd2(acc[3], *reinterpret_cast<h2*>(&raw.w));
}

// convert 4x half2 -> 2x float4
__device__ inline void h8_to_f(const h2 acc[4], float4& A, float4& B) {
    float2 f0 = __half22float2(acc[0]);
    float2 f1 = __half22float2(acc[1]);
    float2 f2 = __half22float2(acc[2]);
    float2 f3 = __half22float2(acc[3]);
    A.x = f0.x; A.y = f0.y; A.z = f1.x; A.w = f1.y;
    B.x = f2.x; B.y = f2.y; B.z = f3.x; B.w = f3.y;
}

__device__ inline void xor_reduce8(float4& A, float4& B) {
#pragma unroll
    for (int m = 8; m <= 32; m <<= 1) {
        A.x += __shfl_xor(A.x, m, 64); A.y += __shfl_xor(A.y, m, 64);
        A.z += __shfl_xor(A.z, m, 64); A.w += __shfl_xor(A.w, m, 64);
        B.x += __shfl_xor(B.x, m, 64); B.y += __shfl_xor(B.y, m, 64);
        B.z += __shfl_xor(B.z, m, 64); B.w += __shfl_xor(B.w, m, 64);
    }
}

// MLP-maximized gather: int4 slot-index loads, v0/v1 interleaved, up to 8 outstanding 128B gathers.
// es lane owns slots [es*4, es*4+4) (+32 in phase 1); xor_reduce8 sums across es groups afterward.
__device__ inline void gather2(const uint4* __restrict__ tn,
                               const int* __restrict__ sl0, const int* __restrict__ sl1,
                               int n0, int n1, int es, int fg, h2 a0[4], h2 a1[4]) {
    int base = es * 4;
    int4 q0 = ((const int4*)sl0)[es];       // slots base..base+3 of v0 (safe: full CAP allocated)
    int4 q1 = ((const int4*)sl1)[es];
    if (base + 0 < n0) acc_h8(a0, tn[q0.x * 8 + fg]);
    if (base + 0 < n1) acc_h8(a1, tn[q1.x * 8 + fg]);
    if (base + 1 < n0) acc_h8(a0, tn[q0.y * 8 + fg]);
    if (base + 1 < n1) acc_h8(a1, tn[q1.y * 8 + fg]);
    if (base + 2 < n0) acc_h8(a0, tn[q0.z * 8 + fg]);
    if (base + 2 < n1) acc_h8(a1, tn[q1.z * 8 + fg]);
    if (base + 3 < n0) acc_h8(a0, tn[q0.w * 8 + fg]);
    if (base + 3 < n1) acc_h8(a1, tn[q1.w * 8 + fg]);
    if (n0 > 32 || n1 > 32) {               // rare phase (deg ~Poisson(16))
        int b2 = 32 + es * 4;
        int4 p0 = ((const int4*)sl0)[8 + es];
        int4 p1 = ((const int4*)sl1)[8 + es];
        if (b2 + 0 < n0) acc_h8(a0, tn[p0.x * 8 + fg]);
        if (b2 + 0 < n1) acc_h8(a1, tn[p1.x * 8 + fg]);
        if (b2 + 1 < n0) acc_h8(a0, tn[p0.y * 8 + fg]);
        if (b2 + 1 < n1) acc_h8(a1, tn[p1.y * 8 + fg]);
        if (b2 + 2 < n0) acc_h8(a0, tn[p0.z * 8 + fg]);
        if (b2 + 2 < n1) acc_h8(a1, tn[p1.z * 8 + fg]);
        if (b2 + 3 < n0) acc_h8(a0, tn[p0.w * 8 + fg]);
        if (b2 + 3 < n1) acc_h8(a1, tn[p1.w * 8 + fg]);
    }
}

// ================= bucket fill: XCD-aligned target-range sweeps + gb + E=emb@W1 ==================
// 4 edges/thread (ext-vector nt loads): 4 independent atomic->store chains in flight per thread to
// hide the ~600-900cy device-scope atomic round-trip (coherent point beyond non-coherent XCD L2s).
__global__ __launch_bounds__(256) void k_fill_slots(const int* __restrict__ row, const int* __restrict__ col,
                                                    int* __restrict__ cnt, int* __restrict__ slots,
                                                    const int* __restrict__ batch, int* __restrict__ start,
                                                    const float* __restrict__ emb, const float* __restrict__ W1,
                                                    float* __restrict__ E) {
    int bid = blockIdx.x;
    if (bid < NSWEEP * EBLK4) {     // ---- fill sweep (XCD-interleaved, 4 edges/thread) ----
        int sweep = bid & (NSWEEP - 1);
        int t = (bid >> 3) * 256 + threadIdx.x;          // quad index
        if (t >= NQUAD) return;
        i4 c4 = __builtin_nontemporal_load((const i4*)col + t);
        unsigned lo = (unsigned)(sweep * RANGE);
        bool m0 = (unsigned)(c4.x - lo) < (unsigned)RANGE;
        bool m1 = (unsigned)(c4.y - lo) < (unsigned)RANGE;
        bool m2 = (unsigned)(c4.z - lo) < (unsigned)RANGE;
        bool m3 = (unsigned)(c4.w - lo) < (unsigned)RANGE;
        if (m0 | m1 | m2 | m3) {
            i4 r4 = __builtin_nontemporal_load((const i4*)row + t);
            if (m0) { int pos = atomicAdd(&cnt[c4.x], 1); if (pos < CAP) slots[c4.x * CAP + pos] = r4.x; }
            if (m1) { int pos = atomicAdd(&cnt[c4.y], 1); if (pos < CAP) slots[c4.y * CAP + pos] = r4.y; }
            if (m2) { int pos = atomicAdd(&cnt[c4.z], 1); if (pos < CAP) slots[c4.z * CAP + pos] = r4.z; }
            if (m3) { int pos = atomicAdd(&cnt[c4.w], 1); if (pos < CAP) slots[c4.w * CAP + pos] = r4.w; }
        }
    } else if (bid < NSWEEP * EBLK4 + NBLK) {  // ---- graph boundaries from sorted batch ----
        int v = (bid - NSWEEP * EBLK4) * 256 + threadIdx.x;
        if (v >= N_NODES) return;
        int b = batch[v];
        int pb = (v == 0) ? -1 : batch[v - 1];
        for (int g = pb + 1; g <= b; ++g) start[g] = v;
        if (v == N_NODES - 1)
            for (int g = b + 1; g <= N_GRAPHS; ++g) start[g] = N_NODES;
    } else {                        // ---- E[j] = emb[j] @ W1 (1000x64, float4/thread) ----
        int t = (bid - NSWEEP * EBLK4 - NBLK) * 256 + threadIdx.x;
        int j = t >> 4;
        int f4 = t & 15;
        if (j >= VOCAB) return;
        const float4* W4 = (const float4*)W1;
        const float* er = emb + j * EMBED;
        float4 acc = make_float4(0.f, 0.f, 0.f, 0.f);
#pragma unroll 8
        for (int k = 0; k < EMBED; ++k) {
            float hv = er[k];
            float4 w = W4[k * 16 + f4];
            acc.x += hv * w.x; acc.y += hv * w.y; acc.z += hv * w.z; acc.w += hv * w.w;
        }
        ((float4*)E)[t] = acc;
    }
}

// ================= tn1[v] = fp16( rsqrt(cnt[v]+1) * E[x[v]] ) =================
__global__ __launch_bounds__(256) void k_tn1(const int* __restrict__ x, const int* __restrict__ cnt,
                                             const float* __restrict__ E, uint2* __restrict__ tn) {
    int t = blockIdx.x * 256 + threadIdx.x;      // exact: N_NODES*16
    int v = t >> 4;
    int f4 = t & 15;
    float d = rsqrtf((float)(cnt[v] + 1));
    float4 a = ((const float4*)E)[x[v] * 16 + f4];
    a.x *= d; a.y *= d; a.z *= d; a.w *= d;
    tn[t] = pack_h4(a);
}

// ================= fused: layer-1 aggregate (fp16 pk-add) + finalize + layer-2 GEMM ==============
// 2 nodes/wave; lane = (es[0..7], fg[0..7]); packed-fp16 per-lane partials, fp32 reduce
__global__ __launch_bounds__(256) void k_agg_gemm(const uint4* __restrict__ tn,
                                                  const int* __restrict__ cnt,
                                                  const int* __restrict__ slots,
                                                  const float* __restrict__ bias,
                                                  const float* __restrict__ W2,
                                                  __half* __restrict__ tn2) {
    __shared__ float hrow[8][HID];
    int wid = threadIdx.x >> 6;
    int lane = threadIdx.x & 63;
    int fg = lane & 7;
    int es = lane >> 3;
    int v0 = blockIdx.x * 8 + wid * 2;
    int v1 = v0 + 1;
    int c0 = cnt[v0], c1 = cnt[v1];
    int n0 = min(c0, CAP), n1 = min(c1, CAP);
    h2 z = __float2half2_rn(0.f);
    h2 a0[4] = {z, z, z, z};
    h2 a1[4] = {z, z, z, z};
    if (es == 0) acc_h8(a0, tn[v0 * 8 + fg]);   // self loop v0
    if (es == 1) acc_h8(a1, tn[v1 * 8 + fg]);   // self loop v1
    gather2(tn, slots + v0 * CAP, slots + v1 * CAP, n0, n1, es, fg, a0, a1);
    float4 a0A, a0B, a1A, a1B;
    h8_to_f(a0, a0A, a0B);
    h8_to_f(a1, a1A, a1B);
    xor_reduce8(a0A, a0B);
    xor_reduce8(a1A, a1B);
    float d0 = rsqrtf((float)(c0 + 1));
    float d1 = rsqrtf((float)(c1 + 1));
    float4 bA = ((const float4*)bias)[fg * 2 + 0];
    float4 bB = ((const float4*)bias)[fg * 2 + 1];
    if (es == 0) {
        float4 oA, oB;
        oA.x = fmaxf(d0 * a0A.x + bA.x, 0.f); oA.y = fmaxf(d0 * a0A.y + bA.y, 0.f);
        oA.z = fmaxf(d0 * a0A.z + bA.z, 0.f); oA.w = fmaxf(d0 * a0A.w + bA.w, 0.f);
        oB.x = fmaxf(d0 * a0B.x + bB.x, 0.f); oB.y = fmaxf(d0 * a0B.y + bB.y, 0.f);
        oB.z = fmaxf(d0 * a0B.z + bB.z, 0.f); oB.w = fmaxf(d0 * a0B.w + bB.w, 0.f);
        ((float4*)&hrow[wid * 2][fg * 8])[0] = oA;
        ((float4*)&hrow[wid * 2][fg * 8])[1] = oB;
    }
    if (es == 1) {
        float4 oA, oB;
        oA.x = fmaxf(d1 * a1A.x + bA.x, 0.f); oA.y = fmaxf(d1 * a1A.y + bA.y, 0.f);
        oA.z = fmaxf(d1 * a1A.z + bA.z, 0.f); oA.w = fmaxf(d1 * a1A.w + bA.w, 0.f);
        oB.x = fmaxf(d1 * a1B.x + bB.x, 0.f); oB.y = fmaxf(d1 * a1B.y + bB.y, 0.f);
        oB.z = fmaxf(d1 * a1B.z + bB.z, 0.f); oB.w = fmaxf(d1 * a1B.w + bB.w, 0.f);
        ((float4*)&hrow[wid * 2 + 1][fg * 8])[0] = oA;
        ((float4*)&hrow[wid * 2 + 1][fg * 8])[1] = oB;
    }
    __syncthreads();
    // ---- layer-2 GEMM: lane computes feature `lane` for both nodes (float4 LDS broadcast reads) ----
    const float4* h04 = (const float4*)hrow[wid * 2];
    const float4* h14 = (const float4*)hrow[wid * 2 + 1];
    float s0 = 0.f, s1 = 0.f;
#pragma unroll 4
    for (int k4 = 0; k4 < 16; ++k4) {
        float4 ha = h04[k4];
        float4 hb = h14[k4];
        int k = k4 * 4;
        float w0 = W2[(k + 0) * HID + lane];
        float w1 = W2[(k + 1) * HID + lane];
        float w2 = W2[(k + 2) * HID + lane];
        float w3 = W2[(k + 3) * HID + lane];
        s0 += ha.x * w0 + ha.y * w1 + ha.z * w2 + ha.w * w3;
        s1 += hb.x * w0 + hb.y * w1 + hb.z * w2 + hb.w * w3;
    }
    tn2[v0 * HID + lane] = __float2half(d0 * s0);
    tn2[v1 * HID + lane] = __float2half(d1 * s1);
}

// ---------------- layer-2 aggregate (fp16 pk-add) — 2 nodes per wave -> h2 (fp32) ----------------
__global__ __launch_bounds__(256) void k_agg(const uint4* __restrict__ tn,
                                             const int* __restrict__ cnt,
                                             const int* __restrict__ slots,
                                             const float* __restrict__ bias,
                                             float* __restrict__ h) {
    int wid = threadIdx.x >> 6;
    int lane = threadIdx.x & 63;
    int fg = lane & 7;
    int es = lane >> 3;
    int v0 = blockIdx.x * 8 + wid * 2;
    int v1 = v0 + 1;
    int c0 = cnt[v0], c1 = cnt[v1];
    int n0 = min(c0, CAP), n1 = min(c1, CAP);
    h2 z = __float2half2_rn(0.f);
    h2 a0[4] = {z, z, z, z};
    h2 a1[4] = {z, z, z, z};
    if (es == 0) acc_h8(a0, tn[v0 * 8 + fg]);
    if (es == 1) acc_h8(a1, tn[v1 * 8 + fg]);
    gather2(tn, slots + v0 * CAP, slots + v1 * CAP, n0, n1, es, fg, a0, a1);
    float4 a0A, a0B, a1A, a1B;
    h8_to_f(a0, a0A, a0B);
    h8_to_f(a1, a1A, a1B);
    xor_reduce8(a0A, a0B);
    xor_reduce8(a1A, a1B);
    float4 bA = ((const float4*)bias)[fg * 2 + 0];
    float4 bB = ((const float4*)bias)[fg * 2 + 1];
    if (es == 0) {
        float d0 = rsqrtf((float)(c0 + 1));
        float4 oA, oB;
        oA.x = fmaxf(d0 * a0A.x + bA.x, 0.f); oA.y = fmaxf(d0 * a0A.y + bA.y, 0.f);
        oA.z = fmaxf(d0 * a0A.z + bA.z, 0.f); oA.w = fmaxf(d0 * a0A.w + bA.w, 0.f);
        oB.x = fmaxf(d0 * a0B.x + bB.x, 0.f); oB.y = fmaxf(d0 * a0B.y + bB.y, 0.f);
        oB.z = fmaxf(d0 * a0B.z + bB.z, 0.f); oB.w = fmaxf(d0 * a0B.w + bB.w, 0.f);
        ((float4*)&h[v0 * HID + fg * 8])[0] = oA;
        ((float4*)&h[v0 * HID + fg * 8])[1] = oB;
    }
    if (es == 1) {
        float d1 = rsqrtf((float)(c1 + 1));
        float4 oA, oB;
        oA.x = fmaxf(d1 * a1A.x + bA.x, 0.f); oA.y = fmaxf(d1 * a1A.y + bA.y, 0.f);
        oA.z = fmaxf(d1 * a1A.z + bA.z, 0.f); oA.w = fmaxf(d1 * a1A.w + bA.w, 0.f);
        oB.x = fmaxf(d1 * a1B.x + bB.x, 0.f); oB.y = fmaxf(d1 * a1B.y + bB.y, 0.f);
        oB.z = fmaxf(d1 * a1B.z + bB.z, 0.f); oB.w = fmaxf(d1 * a1B.w + bB.w, 0.f);
        ((float4*)&h[v1 * HID + fg * 8])[0] = oA;
        ((float4*)&h[v1 * HID + fg * 8])[1] = oB;
    }
}

// ---------------- fused mean-pool + projection ----------------
__global__ __launch_bounds__(256) void k_pool_out(const float* __restrict__ h,
                                                  const int* __restrict__ start,
                                                  const float* __restrict__ Wl,
                                                  const float* __restrict__ bl,
                                                  float* __restrict__ out) {
    int g = (blockIdx.x * 256 + threadIdx.x) >> 6;
    int f = threadIdx.x & 63;
    if (g >= N_GRAPHS) return;
    int s = start[g], e = start[g + 1];
    float acc = 0.f;
    int v = s;
    for (; v + 4 <= e; v += 4) {
        float a0 = h[(v + 0) * HID + f];
        float a1 = h[(v + 1) * HID + f];
        float a2 = h[(v + 2) * HID + f];
        float a3 = h[(v + 3) * HID + f];
        acc += (a0 + a1) + (a2 + a3);
    }
    for (; v < e; ++v) acc += h[v * HID + f];
    float m = acc / fmaxf((float)(e - s), 1.f);
    float p0 = m * Wl[f * N_CL + 0];
    float p1 = m * Wl[f * N_CL + 1];
#pragma unroll
    for (int off = 32; off > 0; off >>= 1) {
        p0 += __shfl_down(p0, off, 64);
        p1 += __shfl_down(p1, off, 64);
    }
    if (f == 0) {
        out[g * N_CL + 0] = p0 + bl[0];
        out[g * N_CL + 1] = p1 + bl[1];
    }
}

extern "C" void kernel_launch(void* const* d_in, const int* in_sizes, int n_in,
                              void* d_out, int out_size, void* d_ws, size_t ws_size,
                              hipStream_t stream) {
    const int*   x     = (const int*)d_in[0];
    const int*   ei    = (const int*)d_in[1];        // [2, E] flat: sources then targets
    const int*   batch = (const int*)d_in[2];
    const float* emb   = (const float*)d_in[3];
    const float* W1    = (const float*)d_in[4];
    const float* b1    = (const float*)d_in[5];
    const float* W2    = (const float*)d_in[6];
    const float* b2    = (const float*)d_in[7];
    const float* Wl    = (const float*)d_in[8];
    const float* bl    = (const float*)d_in[9];
    float* out = (float*)d_out;

    const int* row = ei;             // sources
    const int* col = ei + N_EDGES;   // targets

    // ---- workspace layout (~65 MB) ----
    char* ws = (char*)d_ws;
    size_t off = 0;
    auto alloc = [&](size_t bytes) { char* p = ws + off; off = (off + bytes + 511) & ~(size_t)511; return p; };
    const size_t FEAT_BYTES  = (size_t)N_NODES * HID * sizeof(float);      // 25.6 MB
    const size_t FEATH_BYTES = (size_t)N_NODES * HID * sizeof(__half);     // 12.8 MB
    float* A      = (float*)alloc(FEAT_BYTES);             // tn1 (fp16, low half), later h2 (fp32)
    __half* Bt    = (__half*)alloc(FEATH_BYTES);           // tn2 fp16
    int*   slots  = (int*)  alloc((size_t)N_NODES * CAP * sizeof(int));    // 25.6 MB
    float* E      = (float*)alloc((size_t)VOCAB * HID * sizeof(float));    // 256 KB
    int*   start  = (int*)  alloc((size_t)(N_GRAPHS + 1) * sizeof(int));
    int*   cnt    = (int*)  alloc((size_t)N_NODES * sizeof(int));          // zeroed

    dim3 blk(256);
    dim3 g_fill(NSWEEP * EBLK4 + NBLK + VBLK);    // fill sweeps (4 edges/thread) | gb | E-gemm
    dim3 g_tn1(N_NODES * 16 / 256);               // 6250 exact
    dim3 g_agg(N_NODES / 8);                      // 12500 exact (8 nodes/block, 2/wave)
    dim3 g_po((N_GRAPHS * 64 + 255) / 256);       // 512

    hipMemsetAsync(cnt, 0, (size_t)N_NODES * sizeof(int), stream);

    // ---- single scattered pass, XCD-aligned range sweeps ----
    k_fill_slots<<<g_fill, blk, 0, stream>>>(row, col, cnt, slots, batch, start, emb, W1, E);

    // ---- tn1 = fp16(dinv * E[x]) ----
    k_tn1<<<g_tn1, blk, 0, stream>>>(x, cnt, E, (uint2*)A);

    // ---- layer-1 aggregate (fp16 pk-add, MLP gather) + layer-2 GEMM (tn2 -> fp16) ----
    k_agg_gemm<<<g_agg, blk, 0, stream>>>((const uint4*)A, cnt, slots, b1, W2, Bt);

    // ---- layer-2 aggregate (fp16 pk-add, MLP gather) -> h2 fp32 (A reused) ----
    k_agg<<<g_agg, blk, 0, stream>>>((const uint4*)Bt, cnt, slots, b2, A);

    // ---- fused pool + classify ----
    k_pool_out<<<g_po, blk, 0, stream>>>(A, start, Wl, bl, out);
}